// Round 7
// baseline (1082.013 us; speedup 1.0000x reference)
//
#include <hip/hip_runtime.h>

// ---------------------------------------------------------------------------
// GPT-J attention on MI355X (gfx950), bf16 MFMA pipeline.
// B=2 S=2048 E=4096 H=16 D=256 ROT=64
// R6 (4th resubmit; R3/R4/R6 broker timeouts, R5 container failure --
//     this kernel has never been measured):
//     attn gets T14 async-STAGE split -- K/V(kt+1) prefetched to REGISTERS
//     at iteration top (HBM latency hides under QK/softmax/PV), written to
//     LDS after the post-compute barrier. LDS stays 72 KB (2 blocks/CU).
//     T5 setprio around attn MFMA clusters. GEMMs unchanged from R5.
// ---------------------------------------------------------------------------

typedef __bf16 bf16;
typedef bf16  bf16x4 __attribute__((ext_vector_type(4)));
typedef bf16  bf16x8 __attribute__((ext_vector_type(8)));
typedef float f32x4  __attribute__((ext_vector_type(4)));

#define SEQ 2048
#define ED  4096
#define NH  16
#define HD  256

__device__ __forceinline__ void async_load16(const void* g, void* l) {
  __builtin_amdgcn_global_load_lds(
      (const __attribute__((address_space(1))) void*)g,
      (__attribute__((address_space(3))) void*)l, 16, 0, 0);
}

// ---------------------------------------------------------------------------
// fused fp32 -> bf16 conversion, 4 sources, 4 elems/thread
// ---------------------------------------------------------------------------
__global__ void cvt4_f32_bf16(const float* __restrict__ s0,
                              const float* __restrict__ s1,
                              const float* __restrict__ s2,
                              const float* __restrict__ s3,
                              bf16* __restrict__ d0, bf16* __restrict__ d1,
                              bf16* __restrict__ d2, bf16* __restrict__ d3) {
  int sec = blockIdx.x >> 14;              // 16384 blocks / section
  int idx = ((blockIdx.x & 16383) * 256 + threadIdx.x) * 4;
  const float* s = sec == 0 ? s0 : sec == 1 ? s1 : sec == 2 ? s2 : s3;
  bf16* d = sec == 0 ? d0 : sec == 1 ? d1 : sec == 2 ? d2 : d3;
  float4 v = *(const float4*)(s + idx);
  bf16x4 o;
  o.x = (bf16)v.x; o.y = (bf16)v.y; o.z = (bf16)v.z; o.w = (bf16)v.w;
  *(bf16x4*)(d + idx) = o;
}

__global__ void cvt_f32_bf16(const float* __restrict__ src,
                             bf16* __restrict__ dst, int n) {
  int idx = (blockIdx.x * 256 + threadIdx.x) * 4;
  if (idx < n) {
    float4 v = *(const float4*)(src + idx);
    bf16x4 o;
    o.x = (bf16)v.x; o.y = (bf16)v.y; o.z = (bf16)v.z; o.w = (bf16)v.w;
    *(bf16x4*)(dst + idx) = o;
  }
}

// ---------------------------------------------------------------------------
// 256x256 8-phase bt-GEMM (unchanged from R5).
// Serpentine quadrants, 24 ds_read_b128/K-tile/wave, counted vmcnt.
// ---------------------------------------------------------------------------
__device__ __forceinline__ void stageA(const bf16* __restrict__ g, bf16* lds,
                                       int qoff, int w, int lane) {
#pragma unroll
  for (int j = 0; j < 2; ++j) {
    const int u0 = j * 64 + w * 8;
    const int rb = ((u0 >> 6) << 7) + qoff + (u0 & 63);   // wave's 8-row base
    const int r  = rb + (lane >> 3);
    const int gc = (lane & 7) ^ (r & 7);                  // inverse swizzle
    async_load16(g + (size_t)r * ED + gc * 8, lds + (size_t)rb * 64);
  }
}

__device__ __forceinline__ void stageB(const bf16* __restrict__ g, bf16* lds,
                                       int off, int w, int lane) {
#pragma unroll
  for (int j = 0; j < 2; ++j) {
    const int u0 = j * 64 + w * 8;
    const int rb = ((u0 >> 5) << 6) + off + (u0 & 31);
    const int r  = rb + (lane >> 3);
    const int gc = (lane & 7) ^ (r & 7);
    async_load16(g + (size_t)r * ED + gc * 8, lds + (size_t)rb * 64);
  }
}

#define BARRIER()                                                              \
  do {                                                                         \
    asm volatile("" ::: "memory");                                             \
    __builtin_amdgcn_s_barrier();                                              \
    asm volatile("" ::: "memory");                                             \
  } while (0)

#define LDF_A(dst, Abuf, MH)                                                   \
  _Pragma("unroll") for (int mi = 0; mi < 4; ++mi) {                           \
    const int row_ = wm * 128 + ((MH) * 4 + mi) * 16 + lo;                     \
    _Pragma("unroll") for (int ks = 0; ks < 2; ++ks)                           \
      dst[mi][ks] = *(const bf16x8*)((Abuf) + row_ * 64 +                      \
                      ((((ks << 2) + hi) ^ (row_ & 7)) << 3));                 \
  }

#define LDF_B(dst, Bbuf, NHQ)                                                  \
  _Pragma("unroll") for (int ni = 0; ni < 2; ++ni) {                           \
    const int row_ = wn * 64 + ((NHQ) * 2 + ni) * 16 + lo;                     \
    _Pragma("unroll") for (int ks = 0; ks < 2; ++ks)                           \
      dst[ni][ks] = *(const bf16x8*)((Bbuf) + row_ * 64 +                      \
                      ((((ks << 2) + hi) ^ (row_ & 7)) << 3));                 \
  }

#define MFMA_Q(af, bv, MH, NHQ)                                                \
  do {                                                                         \
    __builtin_amdgcn_s_setprio(1);                                             \
    _Pragma("unroll") for (int mi = 0; mi < 4; ++mi)                           \
      _Pragma("unroll") for (int ni = 0; ni < 2; ++ni)                         \
        _Pragma("unroll") for (int ks = 0; ks < 2; ++ks)                       \
          acc[(MH) * 4 + mi][(NHQ) * 2 + ni] =                                 \
              __builtin_amdgcn_mfma_f32_16x16x32_bf16(                         \
                  af[mi][ks], bv[ni][ks],                                      \
                  acc[(MH) * 4 + mi][(NHQ) * 2 + ni], 0, 0, 0);                \
    __builtin_amdgcn_s_setprio(0);                                             \
  } while (0)

template <int MODE>   // 0 = QKV epilogue (bf16 scatter), 1 = fp32 C
__device__ __forceinline__ void gemm256_body(
    char* smem, const bf16* __restrict__ A, const bf16* __restrict__ W,
    bf16* __restrict__ Qb, bf16* __restrict__ Kb, bf16* __restrict__ Vtmp,
    float* __restrict__ Cf) {
  const int tid = threadIdx.x;
  const int w = tid >> 6, lane = tid & 63;
  const int wm = w >> 2, wn = w & 3;
  const int lo = lane & 15, hi = lane >> 4;

  // XCD-bijective swizzle (grid % 8 == 0); tm fastest for per-XCD W reuse.
  const int nwg = gridDim.x;
  const int id = (blockIdx.x & 7) * (nwg >> 3) + (blockIdx.x >> 3);
  const int tm = id & 15, tn = id >> 4;

  const bf16* Ab = A + (size_t)tm * 256 * ED;
  const bf16* Wb = W + (size_t)tn * 256 * ED;

  bf16* A0 = (bf16*)smem;
  bf16* B0 = (bf16*)(smem + 32768);
  bf16* A1 = (bf16*)(smem + 65536);
  bf16* B1 = (bf16*)(smem + 98304);

  f32x4 acc[8][4] = {};
  bf16x8 a[4][2], b0[2][2], b1[2][2];

  // prologue: issue order must match steady-state roles.
  stageA(Ab, A0, 0, w, lane);       // A-lo(0)
  stageB(Wb, B0, 0, w, lane);       // B-lo(0)
  stageA(Ab, A0, 64, w, lane);      // A-hi(0)
  stageB(Wb, B0, 32, w, lane);      // B-hi(0)
  stageB(Wb + 64, B1, 0, w, lane);  // B-lo(1)
  stageA(Ab + 64, A1, 0, w, lane);  // A-lo(1)
  asm volatile("s_waitcnt vmcnt(8)" ::: "memory");
  BARRIER();

#pragma unroll 2
  for (int t = 0; t < 64; ++t) {
    const int cur = t & 1;
    bf16* At = cur ? A1 : A0;
    bf16* Bt = cur ? B1 : B0;
    bf16* An = cur ? A0 : A1;
    bf16* Bn = cur ? B0 : B1;
    const bf16* gA1p = Ab + ((t + 1) & 63) * 64;
    const bf16* gW1p = Wb + ((t + 1) & 63) * 64;
    const bf16* gA2p = Ab + ((t + 2) & 63) * 64;
    const bf16* gW2p = Wb + ((t + 2) & 63) * 64;

    // ---- q0: quadrant (0,0) ----
    LDF_A(a, At, 0);
    LDF_B(b0, Bt, 0);
    stageA(gA1p, An, 64, w, lane);        // A-hi(t+1)
    BARRIER();
    MFMA_Q(a, b0, 0, 0);
    asm volatile("s_waitcnt vmcnt(6)" ::: "memory");  // retires B-hi(t), A-hi(t)
    BARRIER();

    // ---- q1: quadrant (0,1), reuse A-lo regs ----
    LDF_B(b1, Bt, 1);
    stageB(gW1p, Bn, 32, w, lane);        // B-hi(t+1)
    BARRIER();
    MFMA_Q(a, b1, 0, 1);
    BARRIER();

    // ---- q2: quadrant (1,1), reuse B-hi regs; A regs reloaded ----
    LDF_A(a, At, 1);
    stageB(gW2p, Bt, 0, w, lane);         // B-lo(t+2) into cur (dead since q0)
    BARRIER();
    MFMA_Q(a, b1, 1, 1);
    BARRIER();

    // ---- q3: quadrant (1,0), reuse A-hi + B-lo regs ----
    stageA(gA2p, At, 0, w, lane);         // A-lo(t+2) into cur (dead since q0)
    BARRIER();
    MFMA_Q(a, b0, 1, 0);
    asm volatile("s_waitcnt vmcnt(8)" ::: "memory");  // retires A/B-lo(t+1)
    BARRIER();
  }

  if (MODE == 0) {
    const int widx = tn >> 4;            // 0=Q 1=K 2=V
    const int f0 = (tn & 15) * 256;
    bf16* Ob = widx == 0 ? Qb : (widx == 1 ? Kb : Vtmp);
#pragma unroll
    for (int mi = 0; mi < 8; ++mi)
#pragma unroll
      for (int ni = 0; ni < 4; ++ni)
#pragma unroll
        for (int r = 0; r < 4; ++r) {
          int m = tm * 256 + wm * 128 + mi * 16 + hi * 4 + r;
          int f = f0 + wn * 64 + ni * 16 + lo;
          int b = m >> 11, s = m & 2047;
          int h = f >> 8, d = f & 255;
          Ob[(((size_t)(b * NH + h) * SEQ) + s) * HD + d] = (bf16)acc[mi][ni][r];
        }
  } else {
#pragma unroll
    for (int mi = 0; mi < 8; ++mi)
#pragma unroll
      for (int ni = 0; ni < 4; ++ni)
#pragma unroll
        for (int r = 0; r < 4; ++r) {
          int m = tm * 256 + wm * 128 + mi * 16 + hi * 4 + r;
          int n = tn * 256 + wn * 64 + ni * 16 + lo;
          Cf[(size_t)m * ED + n] = acc[mi][ni][r];
        }
  }
}

__global__ __launch_bounds__(512, 2) void gemm_qkv256(
    const bf16* __restrict__ A, const bf16* __restrict__ W,
    bf16* __restrict__ Qb, bf16* __restrict__ Kb, bf16* __restrict__ Vtmp) {
  extern __shared__ char smem[];
  gemm256_body<0>(smem, A, W, Qb, Kb, Vtmp, nullptr);
}

__global__ __launch_bounds__(512, 2) void gemm_out256(
    const bf16* __restrict__ A, const bf16* __restrict__ W,
    float* __restrict__ C) {
  extern __shared__ char smem[];
  gemm256_body<1>(smem, A, W, nullptr, nullptr, nullptr, C);
}

// ---------------------------------------------------------------------------
// V transpose: (b,h,s,d) -> (b,h,d,s). 64x64 tiles via padded LDS.
// ---------------------------------------------------------------------------
__global__ __launch_bounds__(256) void transpose_v(const bf16* __restrict__ src,
                                                   bf16* __restrict__ dst) {
  __shared__ bf16 T[64][72];
  const int bh = blockIdx.z;
  const int st = blockIdx.x;
  const int dt = blockIdx.y;
  const bf16* S = src + ((size_t)bh * SEQ + st * 64) * HD + dt * 64;
#pragma unroll
  for (int p = 0; p < 2; ++p) {
    int r = p * 32 + (threadIdx.x >> 3), c = (threadIdx.x & 7) * 8;
    *(bf16x8*)&T[r][c] = *(const bf16x8*)(S + (size_t)r * HD + c);
  }
  __syncthreads();
  bf16* D = dst + ((size_t)bh * HD + dt * 64) * SEQ + st * 64;
#pragma unroll
  for (int p = 0; p < 2; ++p) {
    int r = p * 32 + (threadIdx.x >> 3), c = (threadIdx.x & 7) * 8;
    bf16x8 v;
#pragma unroll
    for (int j = 0; j < 8; ++j) v[j] = T[c + j][r];
    *(bf16x8*)(D + (size_t)r * SEQ + c) = v;
  }
}

// ---------------------------------------------------------------------------
// RoPE, vectorized: one thread = 4 interleaved pairs (bf16x8, 16 B).
// ---------------------------------------------------------------------------
__global__ void rope_kernel(bf16* __restrict__ Qb, bf16* __restrict__ Kb,
                            const int* __restrict__ pos_ids,
                            const float* __restrict__ emb) {
  int idx = blockIdx.x * 256 + threadIdx.x;
  int g = idx & 7;
  int s = (idx >> 3) & 2047;
  int h = (idx >> 14) & 15;
  int b = (idx >> 18) & 1;
  int t = idx >> 19;
  bf16* T = t ? Kb : Qb;
  int pos = pos_ids[b * SEQ + s];
  const float* e = emb + pos * 64;
  size_t base = (((size_t)(b * NH + h) * SEQ) + s) * HD + g * 8;
  bf16x8 v = *(bf16x8*)(T + base);
  bf16x8 o;
#pragma unroll
  for (int j = 0; j < 4; ++j) {
    int p = g * 4 + j;
    float sn = e[p], cs = e[32 + p];
    float x0 = (float)v[2 * j], x1 = (float)v[2 * j + 1];
    o[2 * j]     = (bf16)(x0 * cs - x1 * sn);
    o[2 * j + 1] = (bf16)(x1 * cs + x0 * sn);
  }
  *(bf16x8*)(T + base) = o;
}

// ---------------------------------------------------------------------------
// Flash attention (causal), qt-paired for load balance.
// R6: T14 async-STAGE split. Iteration kt prefetches K/V(kt+1) into
// REGISTERS at the top (latency hides under QK/softmax/PV), then writes
// them to LDS after the post-compute barrier. kt=0 staged via
// global_load_lds in the per-half prologue. LDS 72 KB -> 2 blocks/CU.
// T5 setprio around both MFMA clusters.
// ---------------------------------------------------------------------------
__global__ __launch_bounds__(256) void attn_kernel(
    const bf16* __restrict__ Qb, const bf16* __restrict__ Kb,
    const bf16* __restrict__ Vt, bf16* __restrict__ AO) {
  __shared__ bf16 Ks[64 * 256];    // 32 KB
  __shared__ bf16 Vs[256 * 64];    // 32 KB
  __shared__ bf16 Ps[4 * 16 * 64]; // 8 KB, wave-private strips
  const int tid = threadIdx.x;
  const int w = tid >> 6, lane = tid & 63;
  const int lo = lane & 15, hi = lane >> 4;
  const int slot = blockIdx.x;  // 0..15
  const int bh = blockIdx.y;    // 0..31

  const bf16* Qh = Qb + (size_t)bh * SEQ * HD;
  const bf16* Kh = Kb + (size_t)bh * SEQ * HD;
  const bf16* Vh = Vt + (size_t)bh * HD * SEQ;
  const int b = bh >> 4, h = bh & 15;

  // per-thread staging coords (match global_load_lds implicit lane layout)
  const int kci = w * 8;                       // base region index
  const int krr = (lane >> 5);                 // K row-within-region (ci*2+krr)
  const int kcc0 = (lane & 31);                // K chunk before swizzle
  const int vdr = (lane >> 3);                 // V row-within-region (ci*8+vdr)
  const int vcc0 = (lane & 7);

  for (int half = 0; half < 2; ++half) {
    const int qt = half ? (31 - slot) : slot;

    bf16x8 aq[8];
    const int qrow = qt * 64 + w * 16 + lo;
#pragma unroll
    for (int ks = 0; ks < 8; ++ks)
      aq[ks] = *(const bf16x8*)(Qh + (size_t)qrow * HD + ks * 32 + hi * 8);

    f32x4 o[16] = {};
    float mrow[4], lrow[4];
#pragma unroll
    for (int r = 0; r < 4; ++r) { mrow[r] = -3e38f; lrow[r] = 0.f; }

    // prologue: stage tile 0 via global_load_lds
#pragma unroll
    for (int i = 0; i < 8; ++i) {
      int ci = kci + i;
      int r = ci * 2 + krr;
      int cc = kcc0 ^ (r & 7);
      async_load16(Kh + (size_t)r * HD + cc * 8, &Ks[ci * 512]);
    }
#pragma unroll
    for (int i = 0; i < 8; ++i) {
      int ci = kci + i;
      int d = ci * 8 + vdr;
      int cc = vcc0 ^ (d & 7);
      async_load16(Vh + (size_t)d * SEQ + cc * 8, &Vs[ci * 512]);
    }
    __syncthreads();

    for (int kt = 0; kt <= qt; ++kt) {
      // ---- T14: prefetch K/V(kt+1) into registers (issue early) ----
      bf16x8 pk[8], pv[8];
      if (kt < qt) {
#pragma unroll
        for (int i = 0; i < 8; ++i) {
          int ci = kci + i;
          int r = ci * 2 + krr;
          int cc = kcc0 ^ (r & 7);
          pk[i] = *(const bf16x8*)(Kh + (size_t)((kt + 1) * 64 + r) * HD + cc * 8);
        }
#pragma unroll
        for (int i = 0; i < 8; ++i) {
          int ci = kci + i;
          int d = ci * 8 + vdr;
          int cc = vcc0 ^ (d & 7);
          pv[i] = *(const bf16x8*)(Vh + (size_t)d * SEQ + (kt + 1) * 64 + cc * 8);
        }
      }

      // ---- S strip: 16 rows x 64 cols ----
      float sv[4][4];
#pragma unroll
      for (int nt = 0; nt < 4; ++nt) {
        f32x4 sacc = {};
        __builtin_amdgcn_s_setprio(1);
#pragma unroll
        for (int ks = 0; ks < 8; ++ks) {
          int row = nt * 16 + lo;
          bf16x8 bk = *(const bf16x8*)
              &Ks[row * HD + ((((ks << 2) + hi) ^ (row & 7)) << 3)];
          sacc = __builtin_amdgcn_mfma_f32_16x16x32_bf16(aq[ks], bk, sacc, 0, 0, 0);
        }
        __builtin_amdgcn_s_setprio(0);
#pragma unroll
        for (int r = 0; r < 4; ++r) {
          float x = sacc[r] * 0.0625f;
          if (kt == qt) {
            int col = kt * 64 + nt * 16 + lo;
            int row = qt * 64 + w * 16 + hi * 4 + r;
            if (col > row) x = -1e30f;
          }
          sv[nt][r] = x;
        }
      }

      // ---- online softmax ----
      float alpha[4];
#pragma unroll
      for (int r = 0; r < 4; ++r) {
        float mx = fmaxf(fmaxf(sv[0][r], sv[1][r]), fmaxf(sv[2][r], sv[3][r]));
        mx = fmaxf(mx, __shfl_xor(mx, 1));
        mx = fmaxf(mx, __shfl_xor(mx, 2));
        mx = fmaxf(mx, __shfl_xor(mx, 4));
        mx = fmaxf(mx, __shfl_xor(mx, 8));
        float mnew = fmaxf(mrow[r], mx);
        alpha[r] = __expf(mrow[r] - mnew);
        mrow[r] = mnew;
        float sum = 0.f;
#pragma unroll
        for (int nt = 0; nt < 4; ++nt) {
          float p = __expf(sv[nt][r] - mnew);
          sv[nt][r] = p;
          sum += p;
        }
        sum += __shfl_xor(sum, 1);
        sum += __shfl_xor(sum, 2);
        sum += __shfl_xor(sum, 4);
        sum += __shfl_xor(sum, 8);
        lrow[r] = lrow[r] * alpha[r] + sum;
      }

#pragma unroll
      for (int nt2 = 0; nt2 < 16; ++nt2)
#pragma unroll
        for (int r = 0; r < 4; ++r) o[nt2][r] *= alpha[r];

      // ---- P: C-layout -> wave-private swizzled LDS strip -> A-layout ----
#pragma unroll
      for (int nt = 0; nt < 4; ++nt)
#pragma unroll
        for (int r = 0; r < 4; ++r) {
          int prow = hi * 4 + r;
          int chunk = nt * 2 + (lo >> 3);
          Ps[w * 1024 + prow * 64 + (((chunk ^ (prow & 7)) << 3) | (lo & 7))] =
              (bf16)sv[nt][r];
        }
      bf16x8 pa[2];
#pragma unroll
      for (int k2 = 0; k2 < 2; ++k2)
        pa[k2] = *(const bf16x8*)
            &Ps[w * 1024 + lo * 64 + ((((k2 << 2) + hi) ^ (lo & 7)) << 3)];

      // ---- O += P @ V ----
      __builtin_amdgcn_s_setprio(1);
#pragma unroll
      for (int nt2 = 0; nt2 < 16; ++nt2) {
#pragma unroll
        for (int k2 = 0; k2 < 2; ++k2) {
          int row = nt2 * 16 + lo;
          bf16x8 bv = *(const bf16x8*)
              &Vs[row * 64 + ((((k2 << 2) + hi) ^ (row & 7)) << 3)];
          o[nt2] = __builtin_amdgcn_mfma_f32_16x16x32_bf16(pa[k2], bv, o[nt2], 0, 0, 0);
        }
      }
      __builtin_amdgcn_s_setprio(0);

      __syncthreads();  // all waves done reading Ks/Vs(kt)

      // ---- write prefetched tile kt+1 into LDS ----
      if (kt < qt) {
#pragma unroll
        for (int i = 0; i < 8; ++i) {
          int ci = kci + i;
          *(bf16x8*)&Ks[ci * 512 + lane * 8] = pk[i];
          *(bf16x8*)&Vs[ci * 512 + lane * 8] = pv[i];
        }
        __syncthreads();  // publish before next iteration reads
      }
    }

    // epilogue: normalize, write AO as (b, s, h*256+d) bf16
#pragma unroll
    for (int r = 0; r < 4; ++r) {
      float inv = 1.f / lrow[r];
      int srow = qt * 64 + w * 16 + hi * 4 + r;
      size_t base = ((size_t)(b * SEQ + srow)) * ED + h * HD;
#pragma unroll
      for (int nt2 = 0; nt2 < 16; ++nt2)
        AO[base + nt2 * 16 + lo] = (bf16)(o[nt2][r] * inv);
    }
  }
}

// ---------------------------------------------------------------------------
// launch
// ---------------------------------------------------------------------------
extern "C" void kernel_launch(void* const* d_in, const int* in_sizes, int n_in,
                              void* d_out, int out_size, void* d_ws,
                              size_t ws_size, hipStream_t stream) {
  const float* hs  = (const float*)d_in[0];
  const int*   pos = (const int*)d_in[1];
  const float* qw  = (const float*)d_in[2];
  const float* kw  = (const float*)d_in[3];
  const float* vw  = (const float*)d_in[4];
  const float* ow  = (const float*)d_in[5];
  const float* emb = (const float*)d_in[6];
  float* out = (float*)d_out;

  char* ws = (char*)d_ws;
  const size_t MB = 1024 * 1024;
  bf16* Hb   = (bf16*)(ws);
  bf16* AO   = (bf16*)(ws);
  bf16* Wqkv = (bf16*)(ws + 32 * MB);
  bf16* Wo   = (bf16*)(ws + 32 * MB);
  bf16* Vt   = (bf16*)(ws + 64 * MB);
  bf16* Qb   = (bf16*)(ws + 128 * MB);
  bf16* Kb   = (bf16*)(ws + 160 * MB);
  bf16* Vtmp = (bf16*)(ws + 192 * MB);

  const int n = ED * ED;            // 16777216

  static bool s_attr = false;
  if (!s_attr) {
    hipFuncSetAttribute((const void*)gemm_qkv256,
                        hipFuncAttributeMaxDynamicSharedMemorySize, 131072);
    hipFuncSetAttribute((const void*)gemm_out256,
                        hipFuncAttributeMaxDynamicSharedMemorySize, 131072);
    s_attr = true;
  }

  cvt4_f32_bf16<<<65536, 256, 0, stream>>>(
      hs, qw, kw, vw, Hb, Wqkv, Wqkv + (size_t)n, Wqkv + 2 * (size_t)n);

  gemm_qkv256<<<768, 512, 131072, stream>>>(Hb, Wqkv, Qb, Kb, Vtmp);

  cvt_f32_bf16<<<16384, 256, 0, stream>>>(ow, Wo, n);
  transpose_v<<<dim3(32, 4, 32), 256, 0, stream>>>(Vtmp, Vt);

  rope_kernel<<<4096, 256, 0, stream>>>(Qb, Kb, pos, emb);

  attn_kernel<<<dim3(16, 32), 256, 0, stream>>>(Qb, Kb, Vt, AO);

  gemm_out256<<<256, 512, 131072, stream>>>(AO, Wo, out);
}

// Round 8
// 922.038 us; speedup vs baseline: 1.1735x; 1.1735x over previous
//
#include <hip/hip_runtime.h>

// ---------------------------------------------------------------------------
// GPT-J attention on MI355X (gfx950), bf16 MFMA pipeline.
// B=2 S=2048 E=4096 H=16 D=256 ROT=64
// R7: T14 reg-staging REVERTED (measured −70us: reg-staging costs more than
//     gload_lds, per catalog). attn restructured instead: QBLK=128 (8 waves,
//     512 thr, grid 8x32=256 blocks=1/CU), double-buffered K/V with counted
//     vmcnt(8) (GEMM's proven T3/T4 pattern). K/V traffic halves
//     (1.08 GB -> 0.56 GB) and staging overlaps compute. GEMMs = R5.
// ---------------------------------------------------------------------------

typedef __bf16 bf16;
typedef bf16  bf16x4 __attribute__((ext_vector_type(4)));
typedef bf16  bf16x8 __attribute__((ext_vector_type(8)));
typedef float f32x4  __attribute__((ext_vector_type(4)));

#define SEQ 2048
#define ED  4096
#define NH  16
#define HD  256

__device__ __forceinline__ void async_load16(const void* g, void* l) {
  __builtin_amdgcn_global_load_lds(
      (const __attribute__((address_space(1))) void*)g,
      (__attribute__((address_space(3))) void*)l, 16, 0, 0);
}

// ---------------------------------------------------------------------------
// fused fp32 -> bf16 conversion, 4 sources, 4 elems/thread
// ---------------------------------------------------------------------------
__global__ void cvt4_f32_bf16(const float* __restrict__ s0,
                              const float* __restrict__ s1,
                              const float* __restrict__ s2,
                              const float* __restrict__ s3,
                              bf16* __restrict__ d0, bf16* __restrict__ d1,
                              bf16* __restrict__ d2, bf16* __restrict__ d3) {
  int sec = blockIdx.x >> 14;              // 16384 blocks / section
  int idx = ((blockIdx.x & 16383) * 256 + threadIdx.x) * 4;
  const float* s = sec == 0 ? s0 : sec == 1 ? s1 : sec == 2 ? s2 : s3;
  bf16* d = sec == 0 ? d0 : sec == 1 ? d1 : sec == 2 ? d2 : d3;
  float4 v = *(const float4*)(s + idx);
  bf16x4 o;
  o.x = (bf16)v.x; o.y = (bf16)v.y; o.z = (bf16)v.z; o.w = (bf16)v.w;
  *(bf16x4*)(d + idx) = o;
}

__global__ void cvt_f32_bf16(const float* __restrict__ src,
                             bf16* __restrict__ dst, int n) {
  int idx = (blockIdx.x * 256 + threadIdx.x) * 4;
  if (idx < n) {
    float4 v = *(const float4*)(src + idx);
    bf16x4 o;
    o.x = (bf16)v.x; o.y = (bf16)v.y; o.z = (bf16)v.z; o.w = (bf16)v.w;
    *(bf16x4*)(dst + idx) = o;
  }
}

// ---------------------------------------------------------------------------
// 256x256 8-phase bt-GEMM (unchanged from R5).
// Serpentine quadrants, 24 ds_read_b128/K-tile/wave, counted vmcnt.
// ---------------------------------------------------------------------------
__device__ __forceinline__ void stageA(const bf16* __restrict__ g, bf16* lds,
                                       int qoff, int w, int lane) {
#pragma unroll
  for (int j = 0; j < 2; ++j) {
    const int u0 = j * 64 + w * 8;
    const int rb = ((u0 >> 6) << 7) + qoff + (u0 & 63);   // wave's 8-row base
    const int r  = rb + (lane >> 3);
    const int gc = (lane & 7) ^ (r & 7);                  // inverse swizzle
    async_load16(g + (size_t)r * ED + gc * 8, lds + (size_t)rb * 64);
  }
}

__device__ __forceinline__ void stageB(const bf16* __restrict__ g, bf16* lds,
                                       int off, int w, int lane) {
#pragma unroll
  for (int j = 0; j < 2; ++j) {
    const int u0 = j * 64 + w * 8;
    const int rb = ((u0 >> 5) << 6) + off + (u0 & 31);
    const int r  = rb + (lane >> 3);
    const int gc = (lane & 7) ^ (r & 7);
    async_load16(g + (size_t)r * ED + gc * 8, lds + (size_t)rb * 64);
  }
}

#define BARRIER()                                                              \
  do {                                                                         \
    asm volatile("" ::: "memory");                                             \
    __builtin_amdgcn_s_barrier();                                              \
    asm volatile("" ::: "memory");                                             \
  } while (0)

#define LDF_A(dst, Abuf, MH)                                                   \
  _Pragma("unroll") for (int mi = 0; mi < 4; ++mi) {                           \
    const int row_ = wm * 128 + ((MH) * 4 + mi) * 16 + lo;                     \
    _Pragma("unroll") for (int ks = 0; ks < 2; ++ks)                           \
      dst[mi][ks] = *(const bf16x8*)((Abuf) + row_ * 64 +                      \
                      ((((ks << 2) + hi) ^ (row_ & 7)) << 3));                 \
  }

#define LDF_B(dst, Bbuf, NHQ)                                                  \
  _Pragma("unroll") for (int ni = 0; ni < 2; ++ni) {                           \
    const int row_ = wn * 64 + ((NHQ) * 2 + ni) * 16 + lo;                     \
    _Pragma("unroll") for (int ks = 0; ks < 2; ++ks)                           \
      dst[ni][ks] = *(const bf16x8*)((Bbuf) + row_ * 64 +                      \
                      ((((ks << 2) + hi) ^ (row_ & 7)) << 3));                 \
  }

#define MFMA_Q(af, bv, MH, NHQ)                                                \
  do {                                                                         \
    __builtin_amdgcn_s_setprio(1);                                             \
    _Pragma("unroll") for (int mi = 0; mi < 4; ++mi)                           \
      _Pragma("unroll") for (int ni = 0; ni < 2; ++ni)                         \
        _Pragma("unroll") for (int ks = 0; ks < 2; ++ks)                       \
          acc[(MH) * 4 + mi][(NHQ) * 2 + ni] =                                 \
              __builtin_amdgcn_mfma_f32_16x16x32_bf16(                         \
                  af[mi][ks], bv[ni][ks],                                      \
                  acc[(MH) * 4 + mi][(NHQ) * 2 + ni], 0, 0, 0);                \
    __builtin_amdgcn_s_setprio(0);                                             \
  } while (0)

template <int MODE>   // 0 = QKV epilogue (bf16 scatter), 1 = fp32 C
__device__ __forceinline__ void gemm256_body(
    char* smem, const bf16* __restrict__ A, const bf16* __restrict__ W,
    bf16* __restrict__ Qb, bf16* __restrict__ Kb, bf16* __restrict__ Vtmp,
    float* __restrict__ Cf) {
  const int tid = threadIdx.x;
  const int w = tid >> 6, lane = tid & 63;
  const int wm = w >> 2, wn = w & 3;
  const int lo = lane & 15, hi = lane >> 4;

  // XCD-bijective swizzle (grid % 8 == 0); tm fastest for per-XCD W reuse.
  const int nwg = gridDim.x;
  const int id = (blockIdx.x & 7) * (nwg >> 3) + (blockIdx.x >> 3);
  const int tm = id & 15, tn = id >> 4;

  const bf16* Ab = A + (size_t)tm * 256 * ED;
  const bf16* Wb = W + (size_t)tn * 256 * ED;

  bf16* A0 = (bf16*)smem;
  bf16* B0 = (bf16*)(smem + 32768);
  bf16* A1 = (bf16*)(smem + 65536);
  bf16* B1 = (bf16*)(smem + 98304);

  f32x4 acc[8][4] = {};
  bf16x8 a[4][2], b0[2][2], b1[2][2];

  // prologue: issue order must match steady-state roles.
  stageA(Ab, A0, 0, w, lane);       // A-lo(0)
  stageB(Wb, B0, 0, w, lane);       // B-lo(0)
  stageA(Ab, A0, 64, w, lane);      // A-hi(0)
  stageB(Wb, B0, 32, w, lane);      // B-hi(0)
  stageB(Wb + 64, B1, 0, w, lane);  // B-lo(1)
  stageA(Ab + 64, A1, 0, w, lane);  // A-lo(1)
  asm volatile("s_waitcnt vmcnt(8)" ::: "memory");
  BARRIER();

#pragma unroll 2
  for (int t = 0; t < 64; ++t) {
    const int cur = t & 1;
    bf16* At = cur ? A1 : A0;
    bf16* Bt = cur ? B1 : B0;
    bf16* An = cur ? A0 : A1;
    bf16* Bn = cur ? B0 : B1;
    const bf16* gA1p = Ab + ((t + 1) & 63) * 64;
    const bf16* gW1p = Wb + ((t + 1) & 63) * 64;
    const bf16* gA2p = Ab + ((t + 2) & 63) * 64;
    const bf16* gW2p = Wb + ((t + 2) & 63) * 64;

    // ---- q0: quadrant (0,0) ----
    LDF_A(a, At, 0);
    LDF_B(b0, Bt, 0);
    stageA(gA1p, An, 64, w, lane);        // A-hi(t+1)
    BARRIER();
    MFMA_Q(a, b0, 0, 0);
    asm volatile("s_waitcnt vmcnt(6)" ::: "memory");  // retires B-hi(t), A-hi(t)
    BARRIER();

    // ---- q1: quadrant (0,1), reuse A-lo regs ----
    LDF_B(b1, Bt, 1);
    stageB(gW1p, Bn, 32, w, lane);        // B-hi(t+1)
    BARRIER();
    MFMA_Q(a, b1, 0, 1);
    BARRIER();

    // ---- q2: quadrant (1,1), reuse B-hi regs; A regs reloaded ----
    LDF_A(a, At, 1);
    stageB(gW2p, Bt, 0, w, lane);         // B-lo(t+2) into cur (dead since q0)
    BARRIER();
    MFMA_Q(a, b1, 1, 1);
    BARRIER();

    // ---- q3: quadrant (1,0), reuse A-hi + B-lo regs ----
    stageA(gA2p, At, 0, w, lane);         // A-lo(t+2) into cur (dead since q0)
    BARRIER();
    MFMA_Q(a, b0, 1, 0);
    asm volatile("s_waitcnt vmcnt(8)" ::: "memory");  // retires A/B-lo(t+1)
    BARRIER();
  }

  if (MODE == 0) {
    const int widx = tn >> 4;            // 0=Q 1=K 2=V
    const int f0 = (tn & 15) * 256;
    bf16* Ob = widx == 0 ? Qb : (widx == 1 ? Kb : Vtmp);
#pragma unroll
    for (int mi = 0; mi < 8; ++mi)
#pragma unroll
      for (int ni = 0; ni < 4; ++ni)
#pragma unroll
        for (int r = 0; r < 4; ++r) {
          int m = tm * 256 + wm * 128 + mi * 16 + hi * 4 + r;
          int f = f0 + wn * 64 + ni * 16 + lo;
          int b = m >> 11, s = m & 2047;
          int h = f >> 8, d = f & 255;
          Ob[(((size_t)(b * NH + h) * SEQ) + s) * HD + d] = (bf16)acc[mi][ni][r];
        }
  } else {
#pragma unroll
    for (int mi = 0; mi < 8; ++mi)
#pragma unroll
      for (int ni = 0; ni < 4; ++ni)
#pragma unroll
        for (int r = 0; r < 4; ++r) {
          int m = tm * 256 + wm * 128 + mi * 16 + hi * 4 + r;
          int n = tn * 256 + wn * 64 + ni * 16 + lo;
          Cf[(size_t)m * ED + n] = acc[mi][ni][r];
        }
  }
}

__global__ __launch_bounds__(512, 2) void gemm_qkv256(
    const bf16* __restrict__ A, const bf16* __restrict__ W,
    bf16* __restrict__ Qb, bf16* __restrict__ Kb, bf16* __restrict__ Vtmp) {
  extern __shared__ char smem[];
  gemm256_body<0>(smem, A, W, Qb, Kb, Vtmp, nullptr);
}

__global__ __launch_bounds__(512, 2) void gemm_out256(
    const bf16* __restrict__ A, const bf16* __restrict__ W,
    float* __restrict__ C) {
  extern __shared__ char smem[];
  gemm256_body<1>(smem, A, W, nullptr, nullptr, nullptr, C);
}

// ---------------------------------------------------------------------------
// V transpose: (b,h,s,d) -> (b,h,d,s). 64x64 tiles via padded LDS.
// ---------------------------------------------------------------------------
__global__ __launch_bounds__(256) void transpose_v(const bf16* __restrict__ src,
                                                   bf16* __restrict__ dst) {
  __shared__ bf16 T[64][72];
  const int bh = blockIdx.z;
  const int st = blockIdx.x;
  const int dt = blockIdx.y;
  const bf16* S = src + ((size_t)bh * SEQ + st * 64) * HD + dt * 64;
#pragma unroll
  for (int p = 0; p < 2; ++p) {
    int r = p * 32 + (threadIdx.x >> 3), c = (threadIdx.x & 7) * 8;
    *(bf16x8*)&T[r][c] = *(const bf16x8*)(S + (size_t)r * HD + c);
  }
  __syncthreads();
  bf16* D = dst + ((size_t)bh * HD + dt * 64) * SEQ + st * 64;
#pragma unroll
  for (int p = 0; p < 2; ++p) {
    int r = p * 32 + (threadIdx.x >> 3), c = (threadIdx.x & 7) * 8;
    bf16x8 v;
#pragma unroll
    for (int j = 0; j < 8; ++j) v[j] = T[c + j][r];
    *(bf16x8*)(D + (size_t)r * SEQ + c) = v;
  }
}

// ---------------------------------------------------------------------------
// RoPE, vectorized: one thread = 4 interleaved pairs (bf16x8, 16 B).
// ---------------------------------------------------------------------------
__global__ void rope_kernel(bf16* __restrict__ Qb, bf16* __restrict__ Kb,
                            const int* __restrict__ pos_ids,
                            const float* __restrict__ emb) {
  int idx = blockIdx.x * 256 + threadIdx.x;
  int g = idx & 7;
  int s = (idx >> 3) & 2047;
  int h = (idx >> 14) & 15;
  int b = (idx >> 18) & 1;
  int t = idx >> 19;
  bf16* T = t ? Kb : Qb;
  int pos = pos_ids[b * SEQ + s];
  const float* e = emb + pos * 64;
  size_t base = (((size_t)(b * NH + h) * SEQ) + s) * HD + g * 8;
  bf16x8 v = *(bf16x8*)(T + base);
  bf16x8 o;
#pragma unroll
  for (int j = 0; j < 4; ++j) {
    int p = g * 4 + j;
    float sn = e[p], cs = e[32 + p];
    float x0 = (float)v[2 * j], x1 = (float)v[2 * j + 1];
    o[2 * j]     = (bf16)(x0 * cs - x1 * sn);
    o[2 * j + 1] = (bf16)(x1 * cs + x0 * sn);
  }
  *(bf16x8*)(T + base) = o;
}

// ---------------------------------------------------------------------------
// Flash attention (causal), R7 structure:
// QBLK=128 (8 waves x 16 rows), grid (8 slots, 32 bh) = 256 blocks = 1/CU.
// K/V double-buffered in LDS (2x32K + 2x32K + 16K P = 144 KB dynamic),
// staged via global_load_lds with counted vmcnt(8) -- stage kt+2 into the
// buffer freed by kt's compute; never drain to 0 mid-loop.
// Slot pairing (slot, 15-slot) -> every block exactly 34 K-tile iterations.
// Causal mask applied unconditionally per element.
// ---------------------------------------------------------------------------
__global__ __launch_bounds__(512) void attn_kernel(
    const bf16* __restrict__ Qb, const bf16* __restrict__ Kb,
    const bf16* __restrict__ Vt, bf16* __restrict__ AO) {
  extern __shared__ char asmem[];
  bf16* KsB = (bf16*)asmem;                 // 2 x [64 x 256]
  bf16* VsB = (bf16*)(asmem + 65536);       // 2 x [256 x 64]
  bf16* Ps  = (bf16*)(asmem + 131072);      // 8 x [16 x 64]
  const int tid = threadIdx.x;
  const int w = tid >> 6, lane = tid & 63;  // 8 waves
  const int lo = lane & 15, hi = lane >> 4;
  const int slot = blockIdx.x;  // 0..7
  const int bh = blockIdx.y;    // 0..31

  const bf16* Qh = Qb + (size_t)bh * SEQ * HD;
  const bf16* Kh = Kb + (size_t)bh * SEQ * HD;
  const bf16* Vh = Vt + (size_t)bh * HD * SEQ;
  const int b = bh >> 4, h = bh & 15;

  // staging coords: 32 regions of 512 bf16; wave w covers regions w*4..w*4+3
  const int kci = w * 4;
  const int krr = (lane >> 5);                 // K row-within-region
  const int kcc0 = (lane & 31);                // K chunk pre-swizzle
  const int vdr = (lane >> 3);                 // V row-within-region
  const int vcc0 = (lane & 7);

#define ATTN_STAGE(kt_, Kd, Vd)                                                \
  do {                                                                         \
    _Pragma("unroll") for (int i = 0; i < 4; ++i) {                            \
      int ci = kci + i;                                                        \
      int r = ci * 2 + krr;                                                    \
      int cc = kcc0 ^ (r & 7);                                                 \
      async_load16(Kh + ((size_t)((kt_) * 64 + r)) * HD + cc * 8,              \
                   (Kd) + ci * 512);                                           \
    }                                                                          \
    _Pragma("unroll") for (int i = 0; i < 4; ++i) {                            \
      int ci = kci + i;                                                        \
      int d = ci * 8 + vdr;                                                    \
      int cc = vcc0 ^ (d & 7);                                                 \
      async_load16(Vh + (size_t)d * SEQ + (kt_) * 64 + cc * 8,                 \
                   (Vd) + ci * 512);                                           \
    }                                                                          \
  } while (0)

  for (int half = 0; half < 2; ++half) {
    const int qt2 = half ? (15 - slot) : slot;   // super-tile of 128 q rows
    const int kmax = 2 * qt2 + 1;                // causal k-tile bound (>=1)
    const int rowb = qt2 * 128 + w * 16;         // wave's first q row

    bf16x8 aq[8];
    const int qrow = rowb + lo;
#pragma unroll
    for (int ks = 0; ks < 8; ++ks)
      aq[ks] = *(const bf16x8*)(Qh + (size_t)qrow * HD + ks * 32 + hi * 8);

    f32x4 o[16] = {};
    float mrow[4], lrow[4];
#pragma unroll
    for (int r = 0; r < 4; ++r) { mrow[r] = -3e38f; lrow[r] = 0.f; }

    // prologue: kt=0 -> buf0, kt=1 -> buf1 (kmax >= 1 always)
    ATTN_STAGE(0, KsB, VsB);
    ATTN_STAGE(1, KsB + 16384, VsB + 16384);
    asm volatile("s_waitcnt vmcnt(8)" ::: "memory");  // buf0 landed
    BARRIER();

    for (int kt = 0; kt <= kmax; ++kt) {
      const int cur = kt & 1;
      bf16* Ks = KsB + cur * 16384;
      bf16* Vs = VsB + cur * 16384;

      // ---- S strip: 16 rows x 64 cols ----
      float sv[4][4];
#pragma unroll
      for (int nt = 0; nt < 4; ++nt) {
        f32x4 sacc = {};
#pragma unroll
        for (int ks = 0; ks < 8; ++ks) {
          int row = nt * 16 + lo;
          bf16x8 bk = *(const bf16x8*)
              &Ks[row * HD + ((((ks << 2) + hi) ^ (row & 7)) << 3)];
          sacc = __builtin_amdgcn_mfma_f32_16x16x32_bf16(aq[ks], bk, sacc, 0, 0, 0);
        }
#pragma unroll
        for (int r = 0; r < 4; ++r) {
          float x = sacc[r] * 0.0625f;
          int col = kt * 64 + nt * 16 + lo;
          int row = rowb + hi * 4 + r;
          if (col > row) x = -1e30f;   // unconditional causal mask
          sv[nt][r] = x;
        }
      }

      // ---- online softmax (row lives in 16 lanes sharing hi) ----
      float alpha[4];
#pragma unroll
      for (int r = 0; r < 4; ++r) {
        float mx = fmaxf(fmaxf(sv[0][r], sv[1][r]), fmaxf(sv[2][r], sv[3][r]));
        mx = fmaxf(mx, __shfl_xor(mx, 1));
        mx = fmaxf(mx, __shfl_xor(mx, 2));
        mx = fmaxf(mx, __shfl_xor(mx, 4));
        mx = fmaxf(mx, __shfl_xor(mx, 8));
        float mnew = fmaxf(mrow[r], mx);
        alpha[r] = __expf(mrow[r] - mnew);
        mrow[r] = mnew;
        float sum = 0.f;
#pragma unroll
        for (int nt = 0; nt < 4; ++nt) {
          float p = __expf(sv[nt][r] - mnew);
          sv[nt][r] = p;
          sum += p;
        }
        sum += __shfl_xor(sum, 1);
        sum += __shfl_xor(sum, 2);
        sum += __shfl_xor(sum, 4);
        sum += __shfl_xor(sum, 8);
        lrow[r] = lrow[r] * alpha[r] + sum;
      }

      // rescale O by alpha
#pragma unroll
      for (int nt2 = 0; nt2 < 16; ++nt2)
#pragma unroll
        for (int r = 0; r < 4; ++r) o[nt2][r] *= alpha[r];

      // ---- P: C-layout -> wave-private swizzled LDS strip -> A-layout ----
#pragma unroll
      for (int nt = 0; nt < 4; ++nt)
#pragma unroll
        for (int r = 0; r < 4; ++r) {
          int prow = hi * 4 + r;
          int chunk = nt * 2 + (lo >> 3);
          Ps[w * 1024 + prow * 64 + (((chunk ^ (prow & 7)) << 3) | (lo & 7))] =
              (bf16)sv[nt][r];
        }
      bf16x8 pa[2];
#pragma unroll
      for (int k2 = 0; k2 < 2; ++k2)
        pa[k2] = *(const bf16x8*)
            &Ps[w * 1024 + lo * 64 + ((((k2 << 2) + hi) ^ (lo & 7)) << 3)];

      // ---- O += P @ V  (16x64 @ 64x256) ----
#pragma unroll
      for (int nt2 = 0; nt2 < 16; ++nt2) {
#pragma unroll
        for (int k2 = 0; k2 < 2; ++k2) {
          int row = nt2 * 16 + lo;
          bf16x8 bv = *(const bf16x8*)
              &Vs[row * 64 + ((((k2 << 2) + hi) ^ (row & 7)) << 3)];
          o[nt2] = __builtin_amdgcn_mfma_f32_16x16x32_bf16(pa[k2], bv, o[nt2], 0, 0, 0);
        }
      }

      BARRIER();   // all waves done reading buf[cur]

      if (kt + 2 <= kmax) {
        ATTN_STAGE(kt + 2, Ks, Vs);   // refill the just-freed buffer
        asm volatile("s_waitcnt vmcnt(8)" ::: "memory");  // kt+1 landed
      } else {
        asm volatile("s_waitcnt vmcnt(0)" ::: "memory");  // tail drain
      }
      BARRIER();
    }

    // epilogue: normalize, write AO as (b, s, h*256+d) bf16
#pragma unroll
    for (int r = 0; r < 4; ++r) {
      float inv = 1.f / lrow[r];
      int srow = rowb + hi * 4 + r;
      size_t base = ((size_t)(b * SEQ + srow)) * ED + h * HD;
#pragma unroll
      for (int nt2 = 0; nt2 < 16; ++nt2)
        AO[base + nt2 * 16 + lo] = (bf16)(o[nt2][r] * inv);
    }
  }
#undef ATTN_STAGE
}

// ---------------------------------------------------------------------------
// launch
// ---------------------------------------------------------------------------
extern "C" void kernel_launch(void* const* d_in, const int* in_sizes, int n_in,
                              void* d_out, int out_size, void* d_ws,
                              size_t ws_size, hipStream_t stream) {
  const float* hs  = (const float*)d_in[0];
  const int*   pos = (const int*)d_in[1];
  const float* qw  = (const float*)d_in[2];
  const float* kw  = (const float*)d_in[3];
  const float* vw  = (const float*)d_in[4];
  const float* ow  = (const float*)d_in[5];
  const float* emb = (const float*)d_in[6];
  float* out = (float*)d_out;

  char* ws = (char*)d_ws;
  const size_t MB = 1024 * 1024;
  bf16* Hb   = (bf16*)(ws);
  bf16* AO   = (bf16*)(ws);
  bf16* Wqkv = (bf16*)(ws + 32 * MB);
  bf16* Wo   = (bf16*)(ws + 32 * MB);
  bf16* Vt   = (bf16*)(ws + 64 * MB);
  bf16* Qb   = (bf16*)(ws + 128 * MB);
  bf16* Kb   = (bf16*)(ws + 160 * MB);
  bf16* Vtmp = (bf16*)(ws + 192 * MB);

  const int n = ED * ED;            // 16777216

  static bool s_attr = false;
  if (!s_attr) {
    hipFuncSetAttribute((const void*)gemm_qkv256,
                        hipFuncAttributeMaxDynamicSharedMemorySize, 131072);
    hipFuncSetAttribute((const void*)gemm_out256,
                        hipFuncAttributeMaxDynamicSharedMemorySize, 131072);
    hipFuncSetAttribute((const void*)attn_kernel,
                        hipFuncAttributeMaxDynamicSharedMemorySize, 147456);
    s_attr = true;
  }

  cvt4_f32_bf16<<<65536, 256, 0, stream>>>(
      hs, qw, kw, vw, Hb, Wqkv, Wqkv + (size_t)n, Wqkv + 2 * (size_t)n);

  gemm_qkv256<<<768, 512, 131072, stream>>>(Hb, Wqkv, Qb, Kb, Vtmp);

  cvt_f32_bf16<<<16384, 256, 0, stream>>>(ow, Wo, n);
  transpose_v<<<dim3(32, 4, 32), 256, 0, stream>>>(Vtmp, Vt);

  rope_kernel<<<4096, 256, 0, stream>>>(Qb, Kb, pos, emb);

  attn_kernel<<<dim3(8, 32), 512, 147456, stream>>>(Qb, Kb, Vt, AO);

  gemm_out256<<<256, 512, 131072, stream>>>(AO, Wo, out);
}

// Round 9
// 912.671 us; speedup vs baseline: 1.1855x; 1.0103x over previous
//
#include <hip/hip_runtime.h>

// ---------------------------------------------------------------------------
// GPT-J attention on MI355X (gfx950), bf16 MFMA pipeline.
// B=2 S=2048 E=4096 H=16 D=256 ROT=64
// R9: GEMM barrier reduction -- 8 barriers/K-tile -> 2 (B1 after q1, B2
//     after q3), each with publish-pattern vmcnt(4). Hazard pairs:
//     {A-lo,B-lo} read@q0 vs stages@q2/q3 -> B1; {B-hi,A-hi} read@q1/q2
//     vs stages@t+1.q0/q1 -> B2. Steady state: 4 loads outstanding at
//     every tile entry. attn (R7 QBLK=128 dbuf pipeline) unchanged.
// ---------------------------------------------------------------------------

typedef __bf16 bf16;
typedef bf16  bf16x4 __attribute__((ext_vector_type(4)));
typedef bf16  bf16x8 __attribute__((ext_vector_type(8)));
typedef float f32x4  __attribute__((ext_vector_type(4)));

#define SEQ 2048
#define ED  4096
#define NH  16
#define HD  256

__device__ __forceinline__ void async_load16(const void* g, void* l) {
  __builtin_amdgcn_global_load_lds(
      (const __attribute__((address_space(1))) void*)g,
      (__attribute__((address_space(3))) void*)l, 16, 0, 0);
}

// ---------------------------------------------------------------------------
// fused fp32 -> bf16 conversion, 4 sources, 4 elems/thread
// ---------------------------------------------------------------------------
__global__ void cvt4_f32_bf16(const float* __restrict__ s0,
                              const float* __restrict__ s1,
                              const float* __restrict__ s2,
                              const float* __restrict__ s3,
                              bf16* __restrict__ d0, bf16* __restrict__ d1,
                              bf16* __restrict__ d2, bf16* __restrict__ d3) {
  int sec = blockIdx.x >> 14;              // 16384 blocks / section
  int idx = ((blockIdx.x & 16383) * 256 + threadIdx.x) * 4;
  const float* s = sec == 0 ? s0 : sec == 1 ? s1 : sec == 2 ? s2 : s3;
  bf16* d = sec == 0 ? d0 : sec == 1 ? d1 : sec == 2 ? d2 : d3;
  float4 v = *(const float4*)(s + idx);
  bf16x4 o;
  o.x = (bf16)v.x; o.y = (bf16)v.y; o.z = (bf16)v.z; o.w = (bf16)v.w;
  *(bf16x4*)(d + idx) = o;
}

__global__ void cvt_f32_bf16(const float* __restrict__ src,
                             bf16* __restrict__ dst, int n) {
  int idx = (blockIdx.x * 256 + threadIdx.x) * 4;
  if (idx < n) {
    float4 v = *(const float4*)(src + idx);
    bf16x4 o;
    o.x = (bf16)v.x; o.y = (bf16)v.y; o.z = (bf16)v.z; o.w = (bf16)v.w;
    *(bf16x4*)(dst + idx) = o;
  }
}

// ---------------------------------------------------------------------------
// 256x256 bt-GEMM, serpentine quadrants, 24 ds_read_b128/K-tile/wave.
// R9 sync plan (2 barriers/K-tile, publish pattern):
//   q0: read A-lo,B-lo | stage A-hi(t+1)->next | MFMA(0,0)
//   q1: read B-hi      | stage B-hi(t+1)->next | MFMA(0,1)
//       vmcnt(4)  [retires A-lo/B-lo(t+1)]  B1
//   q2: read A-hi      | stage B-lo(t+2)->cur  | MFMA(1,1)
//   q3: (no reads)     | stage A-lo(t+2)->cur  | MFMA(1,0)
//       vmcnt(4)  [retires A-hi/B-hi(t+1)]  B2
// Read-vs-overwrite: cur.{A-lo,B-lo} read@q0, stages@q2/q3 -> B1 between;
// cur.{B-hi,A-hi} read@q1/q2, stages@t+1.{q0,q1} -> B2 between.
// Invariant: 4 loads outstanding entering each tile (matches prologue).
// ---------------------------------------------------------------------------
__device__ __forceinline__ void stageA(const bf16* __restrict__ g, bf16* lds,
                                       int qoff, int w, int lane) {
#pragma unroll
  for (int j = 0; j < 2; ++j) {
    const int u0 = j * 64 + w * 8;
    const int rb = ((u0 >> 6) << 7) + qoff + (u0 & 63);   // wave's 8-row base
    const int r  = rb + (lane >> 3);
    const int gc = (lane & 7) ^ (r & 7);                  // inverse swizzle
    async_load16(g + (size_t)r * ED + gc * 8, lds + (size_t)rb * 64);
  }
}

__device__ __forceinline__ void stageB(const bf16* __restrict__ g, bf16* lds,
                                       int off, int w, int lane) {
#pragma unroll
  for (int j = 0; j < 2; ++j) {
    const int u0 = j * 64 + w * 8;
    const int rb = ((u0 >> 5) << 6) + off + (u0 & 31);
    const int r  = rb + (lane >> 3);
    const int gc = (lane & 7) ^ (r & 7);
    async_load16(g + (size_t)r * ED + gc * 8, lds + (size_t)rb * 64);
  }
}

#define BARRIER()                                                              \
  do {                                                                         \
    asm volatile("" ::: "memory");                                             \
    __builtin_amdgcn_s_barrier();                                              \
    asm volatile("" ::: "memory");                                             \
  } while (0)

#define LDF_A(dst, Abuf, MH)                                                   \
  _Pragma("unroll") for (int mi = 0; mi < 4; ++mi) {                           \
    const int row_ = wm * 128 + ((MH) * 4 + mi) * 16 + lo;                     \
    _Pragma("unroll") for (int ks = 0; ks < 2; ++ks)                           \
      dst[mi][ks] = *(const bf16x8*)((Abuf) + row_ * 64 +                      \
                      ((((ks << 2) + hi) ^ (row_ & 7)) << 3));                 \
  }

#define LDF_B(dst, Bbuf, NHQ)                                                  \
  _Pragma("unroll") for (int ni = 0; ni < 2; ++ni) {                           \
    const int row_ = wn * 64 + ((NHQ) * 2 + ni) * 16 + lo;                     \
    _Pragma("unroll") for (int ks = 0; ks < 2; ++ks)                           \
      dst[ni][ks] = *(const bf16x8*)((Bbuf) + row_ * 64 +                      \
                      ((((ks << 2) + hi) ^ (row_ & 7)) << 3));                 \
  }

#define MFMA_Q(af, bv, MH, NHQ)                                                \
  do {                                                                         \
    __builtin_amdgcn_s_setprio(1);                                             \
    _Pragma("unroll") for (int mi = 0; mi < 4; ++mi)                           \
      _Pragma("unroll") for (int ni = 0; ni < 2; ++ni)                         \
        _Pragma("unroll") for (int ks = 0; ks < 2; ++ks)                       \
          acc[(MH) * 4 + mi][(NHQ) * 2 + ni] =                                 \
              __builtin_amdgcn_mfma_f32_16x16x32_bf16(                         \
                  af[mi][ks], bv[ni][ks],                                      \
                  acc[(MH) * 4 + mi][(NHQ) * 2 + ni], 0, 0, 0);                \
    __builtin_amdgcn_s_setprio(0);                                             \
  } while (0)

template <int MODE>   // 0 = QKV epilogue (bf16 scatter), 1 = fp32 C
__device__ __forceinline__ void gemm256_body(
    char* smem, const bf16* __restrict__ A, const bf16* __restrict__ W,
    bf16* __restrict__ Qb, bf16* __restrict__ Kb, bf16* __restrict__ Vtmp,
    float* __restrict__ Cf) {
  const int tid = threadIdx.x;
  const int w = tid >> 6, lane = tid & 63;
  const int wm = w >> 2, wn = w & 3;
  const int lo = lane & 15, hi = lane >> 4;

  // XCD-bijective swizzle (grid % 8 == 0); tm fastest for per-XCD W reuse.
  const int nwg = gridDim.x;
  const int id = (blockIdx.x & 7) * (nwg >> 3) + (blockIdx.x >> 3);
  const int tm = id & 15, tn = id >> 4;

  const bf16* Ab = A + (size_t)tm * 256 * ED;
  const bf16* Wb = W + (size_t)tn * 256 * ED;

  bf16* A0 = (bf16*)smem;
  bf16* B0 = (bf16*)(smem + 32768);
  bf16* A1 = (bf16*)(smem + 65536);
  bf16* B1 = (bf16*)(smem + 98304);

  f32x4 acc[8][4] = {};
  bf16x8 a[4][2], b0[2][2], b1[2][2];

  // prologue: tile0 full + tile1 A-lo/B-lo. vmcnt(4) retires tile0's 8
  // loads (q0..q2 read them with no further barrier before use).
  stageA(Ab, A0, 0, w, lane);       // A-lo(0)
  stageB(Wb, B0, 0, w, lane);       // B-lo(0)
  stageA(Ab, A0, 64, w, lane);      // A-hi(0)
  stageB(Wb, B0, 32, w, lane);      // B-hi(0)
  stageB(Wb + 64, B1, 0, w, lane);  // B-lo(1)
  stageA(Ab + 64, A1, 0, w, lane);  // A-lo(1)
  asm volatile("s_waitcnt vmcnt(4)" ::: "memory");
  BARRIER();

#pragma unroll 2
  for (int t = 0; t < 64; ++t) {
    const int cur = t & 1;
    bf16* At = cur ? A1 : A0;
    bf16* Bt = cur ? B1 : B0;
    bf16* An = cur ? A0 : A1;
    bf16* Bn = cur ? B0 : B1;
    // wrap-staged tile indices keep vmcnt counts exact at the tail; the
    // wrapped writes land only in dead regions and are never read.
    const bf16* gA1p = Ab + ((t + 1) & 63) * 64;
    const bf16* gW1p = Wb + ((t + 1) & 63) * 64;
    const bf16* gA2p = Ab + ((t + 2) & 63) * 64;
    const bf16* gW2p = Wb + ((t + 2) & 63) * 64;

    // ---- q0: quadrant (0,0) ----
    LDF_A(a, At, 0);
    LDF_B(b0, Bt, 0);
    stageA(gA1p, An, 64, w, lane);        // A-hi(t+1)
    MFMA_Q(a, b0, 0, 0);

    // ---- q1: quadrant (0,1), reuse A-lo regs ----
    LDF_B(b1, Bt, 1);
    stageB(gW1p, Bn, 32, w, lane);        // B-hi(t+1)
    MFMA_Q(a, b1, 0, 1);
    asm volatile("s_waitcnt vmcnt(4)" ::: "memory");  // retires A/B-lo(t+1)
    BARRIER();                                        // B1

    // ---- q2: quadrant (1,1), reuse B-hi regs; A regs reloaded ----
    LDF_A(a, At, 1);
    stageB(gW2p, Bt, 0, w, lane);         // B-lo(t+2) into cur (read@q0 done)
    MFMA_Q(a, b1, 1, 1);

    // ---- q3: quadrant (1,0), reuse A-hi + B-lo regs ----
    stageA(gA2p, At, 0, w, lane);         // A-lo(t+2) into cur (read@q0 done)
    MFMA_Q(a, b0, 1, 0);
    asm volatile("s_waitcnt vmcnt(4)" ::: "memory");  // retires A/B-hi(t+1)
    BARRIER();                                        // B2
  }

  if (MODE == 0) {
    const int widx = tn >> 4;            // 0=Q 1=K 2=V
    const int f0 = (tn & 15) * 256;
    bf16* Ob = widx == 0 ? Qb : (widx == 1 ? Kb : Vtmp);
#pragma unroll
    for (int mi = 0; mi < 8; ++mi)
#pragma unroll
      for (int ni = 0; ni < 4; ++ni)
#pragma unroll
        for (int r = 0; r < 4; ++r) {
          int m = tm * 256 + wm * 128 + mi * 16 + hi * 4 + r;
          int f = f0 + wn * 64 + ni * 16 + lo;
          int b = m >> 11, s = m & 2047;
          int h = f >> 8, d = f & 255;
          Ob[(((size_t)(b * NH + h) * SEQ) + s) * HD + d] = (bf16)acc[mi][ni][r];
        }
  } else {
#pragma unroll
    for (int mi = 0; mi < 8; ++mi)
#pragma unroll
      for (int ni = 0; ni < 4; ++ni)
#pragma unroll
        for (int r = 0; r < 4; ++r) {
          int m = tm * 256 + wm * 128 + mi * 16 + hi * 4 + r;
          int n = tn * 256 + wn * 64 + ni * 16 + lo;
          Cf[(size_t)m * ED + n] = acc[mi][ni][r];
        }
  }
}

__global__ __launch_bounds__(512, 2) void gemm_qkv256(
    const bf16* __restrict__ A, const bf16* __restrict__ W,
    bf16* __restrict__ Qb, bf16* __restrict__ Kb, bf16* __restrict__ Vtmp) {
  extern __shared__ char smem[];
  gemm256_body<0>(smem, A, W, Qb, Kb, Vtmp, nullptr);
}

__global__ __launch_bounds__(512, 2) void gemm_out256(
    const bf16* __restrict__ A, const bf16* __restrict__ W,
    float* __restrict__ C) {
  extern __shared__ char smem[];
  gemm256_body<1>(smem, A, W, nullptr, nullptr, nullptr, C);
}

// ---------------------------------------------------------------------------
// V transpose: (b,h,s,d) -> (b,h,d,s). 64x64 tiles via padded LDS.
// ---------------------------------------------------------------------------
__global__ __launch_bounds__(256) void transpose_v(const bf16* __restrict__ src,
                                                   bf16* __restrict__ dst) {
  __shared__ bf16 T[64][72];
  const int bh = blockIdx.z;
  const int st = blockIdx.x;
  const int dt = blockIdx.y;
  const bf16* S = src + ((size_t)bh * SEQ + st * 64) * HD + dt * 64;
#pragma unroll
  for (int p = 0; p < 2; ++p) {
    int r = p * 32 + (threadIdx.x >> 3), c = (threadIdx.x & 7) * 8;
    *(bf16x8*)&T[r][c] = *(const bf16x8*)(S + (size_t)r * HD + c);
  }
  __syncthreads();
  bf16* D = dst + ((size_t)bh * HD + dt * 64) * SEQ + st * 64;
#pragma unroll
  for (int p = 0; p < 2; ++p) {
    int r = p * 32 + (threadIdx.x >> 3), c = (threadIdx.x & 7) * 8;
    bf16x8 v;
#pragma unroll
    for (int j = 0; j < 8; ++j) v[j] = T[c + j][r];
    *(bf16x8*)(D + (size_t)r * SEQ + c) = v;
  }
}

// ---------------------------------------------------------------------------
// RoPE, vectorized: one thread = 4 interleaved pairs (bf16x8, 16 B).
// ---------------------------------------------------------------------------
__global__ void rope_kernel(bf16* __restrict__ Qb, bf16* __restrict__ Kb,
                            const int* __restrict__ pos_ids,
                            const float* __restrict__ emb) {
  int idx = blockIdx.x * 256 + threadIdx.x;
  int g = idx & 7;
  int s = (idx >> 3) & 2047;
  int h = (idx >> 14) & 15;
  int b = (idx >> 18) & 1;
  int t = idx >> 19;
  bf16* T = t ? Kb : Qb;
  int pos = pos_ids[b * SEQ + s];
  const float* e = emb + pos * 64;
  size_t base = (((size_t)(b * NH + h) * SEQ) + s) * HD + g * 8;
  bf16x8 v = *(bf16x8*)(T + base);
  bf16x8 o;
#pragma unroll
  for (int j = 0; j < 4; ++j) {
    int p = g * 4 + j;
    float sn = e[p], cs = e[32 + p];
    float x0 = (float)v[2 * j], x1 = (float)v[2 * j + 1];
    o[2 * j]     = (bf16)(x0 * cs - x1 * sn);
    o[2 * j + 1] = (bf16)(x1 * cs + x0 * sn);
  }
  *(bf16x8*)(T + base) = o;
}

// ---------------------------------------------------------------------------
// Flash attention (causal), R7 structure (unchanged):
// QBLK=128 (8 waves x 16 rows), grid (8 slots, 32 bh) = 256 blocks = 1/CU.
// K/V double-buffered in LDS (144 KB dynamic), counted vmcnt(8).
// ---------------------------------------------------------------------------
__global__ __launch_bounds__(512) void attn_kernel(
    const bf16* __restrict__ Qb, const bf16* __restrict__ Kb,
    const bf16* __restrict__ Vt, bf16* __restrict__ AO) {
  extern __shared__ char asmem[];
  bf16* KsB = (bf16*)asmem;                 // 2 x [64 x 256]
  bf16* VsB = (bf16*)(asmem + 65536);       // 2 x [256 x 64]
  bf16* Ps  = (bf16*)(asmem + 131072);      // 8 x [16 x 64]
  const int tid = threadIdx.x;
  const int w = tid >> 6, lane = tid & 63;  // 8 waves
  const int lo = lane & 15, hi = lane >> 4;
  const int slot = blockIdx.x;  // 0..7
  const int bh = blockIdx.y;    // 0..31

  const bf16* Qh = Qb + (size_t)bh * SEQ * HD;
  const bf16* Kh = Kb + (size_t)bh * SEQ * HD;
  const bf16* Vh = Vt + (size_t)bh * HD * SEQ;
  const int b = bh >> 4, h = bh & 15;

  // staging coords: 32 regions of 512 bf16; wave w covers regions w*4..w*4+3
  const int kci = w * 4;
  const int krr = (lane >> 5);                 // K row-within-region
  const int kcc0 = (lane & 31);                // K chunk pre-swizzle
  const int vdr = (lane >> 3);                 // V row-within-region
  const int vcc0 = (lane & 7);

#define ATTN_STAGE(kt_, Kd, Vd)                                                \
  do {                                                                         \
    _Pragma("unroll") for (int i = 0; i < 4; ++i) {                            \
      int ci = kci + i;                                                        \
      int r = ci * 2 + krr;                                                    \
      int cc = kcc0 ^ (r & 7);                                                 \
      async_load16(Kh + ((size_t)((kt_) * 64 + r)) * HD + cc * 8,              \
                   (Kd) + ci * 512);                                           \
    }                                                                          \
    _Pragma("unroll") for (int i = 0; i < 4; ++i) {                            \
      int ci = kci + i;                                                        \
      int d = ci * 8 + vdr;                                                    \
      int cc = vcc0 ^ (d & 7);                                                 \
      async_load16(Vh + (size_t)d * SEQ + (kt_) * 64 + cc * 8,                 \
                   (Vd) + ci * 512);                                           \
    }                                                                          \
  } while (0)

  for (int half = 0; half < 2; ++half) {
    const int qt2 = half ? (15 - slot) : slot;   // super-tile of 128 q rows
    const int kmax = 2 * qt2 + 1;                // causal k-tile bound (>=1)
    const int rowb = qt2 * 128 + w * 16;         // wave's first q row

    bf16x8 aq[8];
    const int qrow = rowb + lo;
#pragma unroll
    for (int ks = 0; ks < 8; ++ks)
      aq[ks] = *(const bf16x8*)(Qh + (size_t)qrow * HD + ks * 32 + hi * 8);

    f32x4 o[16] = {};
    float mrow[4], lrow[4];
#pragma unroll
    for (int r = 0; r < 4; ++r) { mrow[r] = -3e38f; lrow[r] = 0.f; }

    // prologue: kt=0 -> buf0, kt=1 -> buf1 (kmax >= 1 always)
    ATTN_STAGE(0, KsB, VsB);
    ATTN_STAGE(1, KsB + 16384, VsB + 16384);
    asm volatile("s_waitcnt vmcnt(8)" ::: "memory");  // buf0 landed
    BARRIER();

    for (int kt = 0; kt <= kmax; ++kt) {
      const int cur = kt & 1;
      bf16* Ks = KsB + cur * 16384;
      bf16* Vs = VsB + cur * 16384;

      // ---- S strip: 16 rows x 64 cols ----
      float sv[4][4];
#pragma unroll
      for (int nt = 0; nt < 4; ++nt) {
        f32x4 sacc = {};
#pragma unroll
        for (int ks = 0; ks < 8; ++ks) {
          int row = nt * 16 + lo;
          bf16x8 bk = *(const bf16x8*)
              &Ks[row * HD + ((((ks << 2) + hi) ^ (row & 7)) << 3)];
          sacc = __builtin_amdgcn_mfma_f32_16x16x32_bf16(aq[ks], bk, sacc, 0, 0, 0);
        }
#pragma unroll
        for (int r = 0; r < 4; ++r) {
          float x = sacc[r] * 0.0625f;
          int col = kt * 64 + nt * 16 + lo;
          int row = rowb + hi * 4 + r;
          if (col > row) x = -1e30f;   // unconditional causal mask
          sv[nt][r] = x;
        }
      }

      // ---- online softmax (row lives in 16 lanes sharing hi) ----
      float alpha[4];
#pragma unroll
      for (int r = 0; r < 4; ++r) {
        float mx = fmaxf(fmaxf(sv[0][r], sv[1][r]), fmaxf(sv[2][r], sv[3][r]));
        mx = fmaxf(mx, __shfl_xor(mx, 1));
        mx = fmaxf(mx, __shfl_xor(mx, 2));
        mx = fmaxf(mx, __shfl_xor(mx, 4));
        mx = fmaxf(mx, __shfl_xor(mx, 8));
        float mnew = fmaxf(mrow[r], mx);
        alpha[r] = __expf(mrow[r] - mnew);
        mrow[r] = mnew;
        float sum = 0.f;
#pragma unroll
        for (int nt = 0; nt < 4; ++nt) {
          float p = __expf(sv[nt][r] - mnew);
          sv[nt][r] = p;
          sum += p;
        }
        sum += __shfl_xor(sum, 1);
        sum += __shfl_xor(sum, 2);
        sum += __shfl_xor(sum, 4);
        sum += __shfl_xor(sum, 8);
        lrow[r] = lrow[r] * alpha[r] + sum;
      }

      // rescale O by alpha
#pragma unroll
      for (int nt2 = 0; nt2 < 16; ++nt2)
#pragma unroll
        for (int r = 0; r < 4; ++r) o[nt2][r] *= alpha[r];

      // ---- P: C-layout -> wave-private swizzled LDS strip -> A-layout ----
#pragma unroll
      for (int nt = 0; nt < 4; ++nt)
#pragma unroll
        for (int r = 0; r < 4; ++r) {
          int prow = hi * 4 + r;
          int chunk = nt * 2 + (lo >> 3);
          Ps[w * 1024 + prow * 64 + (((chunk ^ (prow & 7)) << 3) | (lo & 7))] =
              (bf16)sv[nt][r];
        }
      bf16x8 pa[2];
#pragma unroll
      for (int k2 = 0; k2 < 2; ++k2)
        pa[k2] = *(const bf16x8*)
            &Ps[w * 1024 + lo * 64 + ((((k2 << 2) + hi) ^ (lo & 7)) << 3)];

      // ---- O += P @ V  (16x64 @ 64x256) ----
#pragma unroll
      for (int nt2 = 0; nt2 < 16; ++nt2) {
#pragma unroll
        for (int k2 = 0; k2 < 2; ++k2) {
          int row = nt2 * 16 + lo;
          bf16x8 bv = *(const bf16x8*)
              &Vs[row * 64 + ((((k2 << 2) + hi) ^ (row & 7)) << 3)];
          o[nt2] = __builtin_amdgcn_mfma_f32_16x16x32_bf16(pa[k2], bv, o[nt2], 0, 0, 0);
        }
      }

      BARRIER();   // all waves done reading buf[cur]

      if (kt + 2 <= kmax) {
        ATTN_STAGE(kt + 2, Ks, Vs);   // refill the just-freed buffer
        asm volatile("s_waitcnt vmcnt(8)" ::: "memory");  // kt+1 landed
      } else {
        asm volatile("s_waitcnt vmcnt(0)" ::: "memory");  // tail drain
      }
      BARRIER();
    }

    // epilogue: normalize, write AO as (b, s, h*256+d) bf16
#pragma unroll
    for (int r = 0; r < 4; ++r) {
      float inv = 1.f / lrow[r];
      int srow = rowb + hi * 4 + r;
      size_t base = ((size_t)(b * SEQ + srow)) * ED + h * HD;
#pragma unroll
      for (int nt2 = 0; nt2 < 16; ++nt2)
        AO[base + nt2 * 16 + lo] = (bf16)(o[nt2][r] * inv);
    }
  }
#undef ATTN_STAGE
}

// ---------------------------------------------------------------------------
// launch
// ---------------------------------------------------------------------------
extern "C" void kernel_launch(void* const* d_in, const int* in_sizes, int n_in,
                              void* d_out, int out_size, void* d_ws,
                              size_t ws_size, hipStream_t stream) {
  const float* hs  = (const float*)d_in[0];
  const int*   pos = (const int*)d_in[1];
  const float* qw  = (const float*)d_in[2];
  const float* kw  = (const float*)d_in[3];
  const float* vw  = (const float*)d_in[4];
  const float* ow  = (const float*)d_in[5];
  const float* emb = (const float*)d_in[6];
  float* out = (float*)d_out;

  char* ws = (char*)d_ws;
  const size_t MB = 1024 * 1024;
  bf16* Hb   = (bf16*)(ws);
  bf16* AO   = (bf16*)(ws);
  bf16* Wqkv = (bf16*)(ws + 32 * MB);
  bf16* Wo   = (bf16*)(ws + 32 * MB);
  bf16* Vt   = (bf16*)(ws + 64 * MB);
  bf16* Qb   = (bf16*)(ws + 128 * MB);
  bf16* Kb   = (bf16*)(ws + 160 * MB);
  bf16* Vtmp = (bf16*)(ws + 192 * MB);

  const int n = ED * ED;            // 16777216

  static bool s_attr = false;
  if (!s_attr) {
    hipFuncSetAttribute((const void*)gemm_qkv256,
                        hipFuncAttributeMaxDynamicSharedMemorySize, 131072);
    hipFuncSetAttribute((const void*)gemm_out256,
                        hipFuncAttributeMaxDynamicSharedMemorySize, 131072);
    hipFuncSetAttribute((const void*)attn_kernel,
                        hipFuncAttributeMaxDynamicSharedMemorySize, 147456);
    s_attr = true;
  }

  cvt4_f32_bf16<<<65536, 256, 0, stream>>>(
      hs, qw, kw, vw, Hb, Wqkv, Wqkv + (size_t)n, Wqkv + 2 * (size_t)n);

  gemm_qkv256<<<768, 512, 131072, stream>>>(Hb, Wqkv, Qb, Kb, Vtmp);

  cvt_f32_bf16<<<16384, 256, 0, stream>>>(ow, Wo, n);
  transpose_v<<<dim3(32, 4, 32), 256, 0, stream>>>(Vtmp, Vt);

  rope_kernel<<<4096, 256, 0, stream>>>(Qb, Kb, pos, emb);

  attn_kernel<<<dim3(8, 32), 512, 147456, stream>>>(Qb, Kb, Vt, AO);

  gemm_out256<<<256, 512, 131072, stream>>>(AO, Wo, out);
}